// Round 2
// baseline (40118.033 us; speedup 1.0000x reference)
//
#include <hip/hip_runtime.h>
#include <hip/hip_bf16.h>
#include <cstdint>
#include <cstddef>
#include <type_traits>

// Problem: 2-layer LSTM, B=32, T=2048, D=H=512, 4H=2048.
//
// ws layout (bytes):
//   i2h  [T][B][4H] bf16 : off 0,          size 268435456
//   y0   [B][T][H]  bf16 : off 268435456,  size 67108864
//   Whb0 [2048][512] bf16: off 335544320,  size 2097152
//   Whb1 [2048][512] bf16: off 337641472,  size 2097152
//   h0a  [B][H]     bf16 : off 339738624,  size 32768
//   h0b                  : off 339771392
//   h1a                  : off 339804160
//   h1b                  : off 339836928
//   c0   [B][H]     f32  : off 339869696,  size 65536
//   c1                   : off 339935232
// Barrier counters live in d_out's finals region (overwritten by copy_finals).

typedef __attribute__((ext_vector_type(8))) short short8;   // 8 x bf16
typedef __attribute__((ext_vector_type(4))) short short4v;  // 4 x bf16
typedef __attribute__((ext_vector_type(4))) float f32x4;
typedef __attribute__((ext_vector_type(4))) int int4v;

#define MFMA_BF16_16x16x32(A_, B_, C_) \
    __builtin_amdgcn_mfma_f32_16x16x32_bf16(A_, B_, C_, 0, 0, 0)

__device__ __forceinline__ short f2bf(float f) {
    __hip_bfloat16 b = __float2bfloat16(f);
    return *reinterpret_cast<short*>(&b);
}
__device__ __forceinline__ float bflo(uint u) {
    union { uint i; float f; } x; x.i = u << 16; return x.f;
}
__device__ __forceinline__ float bfhi(uint u) {
    union { uint i; float f; } x; x.i = u & 0xffff0000u; return x.f;
}

// ---------------------------------------------------------------------------
// fp32 -> bf16 elementwise convert (for Wh weights), one float4 per thread.
// ---------------------------------------------------------------------------
__global__ __launch_bounds__(256) void cvt_f32_bf16(
    const float* __restrict__ in, __hip_bfloat16* __restrict__ outp)
{
    const int i = blockIdx.x * 256 + threadIdx.x;
    const float4 v = ((const float4*)in)[i];
    short4v o;
    o[0] = f2bf(v.x); o[1] = f2bf(v.y); o[2] = f2bf(v.z); o[3] = f2bf(v.w);
    ((short4v*)outp)[i] = o;
}

// ---------------------------------------------------------------------------
// i2h GEMM: C[(t*32+b)][n] = sum_k A[m][k] * W[n][k] + bi[n] + bh[n]
// A: [M=65536, K=512] row-major, dtype AT (float for layer0, bf16 for layer1)
//    (m = b*2048 + t)
// W: [N=2048, K=512] fp32 row-major, converted to bf16 during staging
// out: [T][B][N] bf16  (index (t*32+b)*N + n)
// 128x128 tile, BK=32, 256 threads (4 waves, 2x2 wave quadrants of 64x64)
// ---------------------------------------------------------------------------
template <typename AT>
__global__ __launch_bounds__(256) void lstm_gemm_i2h(
    const AT* __restrict__ A,
    const float* __restrict__ W,
    const float* __restrict__ bi,
    const float* __restrict__ bh,
    __hip_bfloat16* __restrict__ out)
{
    constexpr int K = 512;
    constexpr int N = 2048;
    const int tid  = threadIdx.x;
    const int lane = tid & 63;
    const int w    = tid >> 6;
    const int wm   = w >> 1, wn = w & 1;
    const int quad = lane >> 4, l15 = lane & 15;
    const int m0 = blockIdx.y * 128;
    const int n0 = blockIdx.x * 128;

    __shared__ __align__(16) short sA[128 * 32];
    __shared__ __align__(16) short sB[128 * 32];

    f32x4 acc[4][4] = {};

    // fp32 staging coords: 2 threads per row, 16 floats each
    const int frow = tid >> 1;         // 0..127
    const int fcol = (tid & 1) * 16;   // 0 or 16
    // bf16 staging coords: 4 threads per row, 8 shorts each, 2 rows/thread
    const int brow = tid >> 2;         // 0..63
    const int bcol = (tid & 3) * 8;    // 0,8,16,24

    for (int k0 = 0; k0 < K; k0 += 32) {
        __syncthreads();
        // ---- stage A ----
        if constexpr (std::is_same<AT, float>::value) {
            const float* ap = A + (size_t)(m0 + frow) * K + k0 + fcol;
            float4 v0 = ((const float4*)ap)[0];
            float4 v1 = ((const float4*)ap)[1];
            float4 v2 = ((const float4*)ap)[2];
            float4 v3 = ((const float4*)ap)[3];
            short8 lo, hi;
            lo[0]=f2bf(v0.x); lo[1]=f2bf(v0.y); lo[2]=f2bf(v0.z); lo[3]=f2bf(v0.w);
            lo[4]=f2bf(v1.x); lo[5]=f2bf(v1.y); lo[6]=f2bf(v1.z); lo[7]=f2bf(v1.w);
            hi[0]=f2bf(v2.x); hi[1]=f2bf(v2.y); hi[2]=f2bf(v2.z); hi[3]=f2bf(v2.w);
            hi[4]=f2bf(v3.x); hi[5]=f2bf(v3.y); hi[6]=f2bf(v3.z); hi[7]=f2bf(v3.w);
            *(short8*)&sA[frow * 32 + fcol]     = lo;
            *(short8*)&sA[frow * 32 + fcol + 8] = hi;
        } else {
            const int4v a0 = *(const int4v*)((const short*)A + (size_t)(m0 + brow) * K + k0 + bcol);
            const int4v a1 = *(const int4v*)((const short*)A + (size_t)(m0 + brow + 64) * K + k0 + bcol);
            *(int4v*)&sA[brow * 32 + bcol]        = a0;
            *(int4v*)&sA[(brow + 64) * 32 + bcol] = a1;
        }
        // ---- stage W (always fp32 -> bf16) ----
        {
            const float* wp = W + (size_t)(n0 + frow) * K + k0 + fcol;
            float4 v0 = ((const float4*)wp)[0];
            float4 v1 = ((const float4*)wp)[1];
            float4 v2 = ((const float4*)wp)[2];
            float4 v3 = ((const float4*)wp)[3];
            short8 lo, hi;
            lo[0]=f2bf(v0.x); lo[1]=f2bf(v0.y); lo[2]=f2bf(v0.z); lo[3]=f2bf(v0.w);
            lo[4]=f2bf(v1.x); lo[5]=f2bf(v1.y); lo[6]=f2bf(v1.z); lo[7]=f2bf(v1.w);
            hi[0]=f2bf(v2.x); hi[1]=f2bf(v2.y); hi[2]=f2bf(v2.z); hi[3]=f2bf(v2.w);
            hi[4]=f2bf(v3.x); hi[5]=f2bf(v3.y); hi[6]=f2bf(v3.z); hi[7]=f2bf(v3.w);
            *(short8*)&sB[frow * 32 + fcol]     = lo;
            *(short8*)&sB[frow * 32 + fcol + 8] = hi;
        }
        __syncthreads();

        short8 aF[4], bF[4];
        #pragma unroll
        for (int i = 0; i < 4; ++i) {
            aF[i] = *(const short8*)&sA[(wm * 64 + i * 16 + l15) * 32 + quad * 8];
            bF[i] = *(const short8*)&sB[(wn * 64 + i * 16 + l15) * 32 + quad * 8];
        }
        #pragma unroll
        for (int mi = 0; mi < 4; ++mi)
            #pragma unroll
            for (int ni = 0; ni < 4; ++ni)
                acc[mi][ni] = MFMA_BF16_16x16x32(aF[mi], bF[ni], acc[mi][ni]);
    }

    // epilogue: D row = quad*4 + r (m), col = l15 (n); scatter m -> (t*32+b)
    #pragma unroll
    for (int ni = 0; ni < 4; ++ni) {
        const int n = n0 + wn * 64 + ni * 16 + l15;
        const float bias = bi[n] + bh[n];
        #pragma unroll
        for (int mi = 0; mi < 4; ++mi) {
            #pragma unroll
            for (int r = 0; r < 4; ++r) {
                const int m = m0 + wm * 64 + mi * 16 + quad * 4 + r;
                const int b = m >> 11;      // m / 2048
                const int t = m & 2047;     // m % 2048
                out[(size_t)(t * 32 + b) * N + n] = __float2bfloat16(acc[mi][ni][r] + bias);
            }
        }
    }
}

// ---------------------------------------------------------------------------
// Persistent recurrence kernel: all 2048 timesteps in ONE launch.
//
// Grid: 16 blocks x 512 threads (8 waves). Block j owns h-columns
// [j*32, j*32+32) for ALL 4 gates (= 128 rows of Wh).
// Wave w (0..7): gate = w&3, col-half = w>>2. Its 16 Wh rows are held
// REGISTER-RESIDENT for the whole sequence (short8 wfrag[16] = 64 VGPRs).
//
// Per step:
//   GEMM  : gates[32b][16n] per wave = 2 chains x 16 MFMA, A (=h_prev) read
//           straight from global (LLC), B from wfrag registers.
//   LDS exchange gl[4][32][34] (f32, padded) -> elementwise owns (b, col pair),
//           c state lives in registers across all 2048 steps.
//   i2h for step t+1 prefetched into registers during step t.
//
// Inter-block barrier (hang-proof, single-spinner):
//   __syncthreads() drains all waves' stores (vmcnt 0 per wave);
//   tid 0 does a RELEASE fetch_add (agent scope: L2 writeback precedes the
//   add), then spins with RELAXED loads + s_sleep; on arrival does one
//   agent ACQUIRE fence (invalidates the block's shared L1 + XCD L2 — a
//   workgroup runs on a single CU), then __syncthreads() releases the block.
//   The spin is iteration-capped: on timeout an LDS flag makes the block
//   skip all future barriers (wrong answer, NOT a hung container).
// 16 blocks on 256 CUs -> co-residency guaranteed (no deadlock).
// ---------------------------------------------------------------------------
template <typename YT>
__global__ __launch_bounds__(512, 2) void lstm_persist(
    const __hip_bfloat16* __restrict__ i2h,   // [T][32][2048]
    const __hip_bfloat16* __restrict__ Wh,    // [2048][512] bf16
    __hip_bfloat16* __restrict__ hA,          // [32][512] read at even t
    __hip_bfloat16* __restrict__ hB,          // [32][512] read at odd t
    float* __restrict__ c_out,                // [32][512] written once at end
    YT* __restrict__ y,                       // [B][T][H]
    int* __restrict__ cnt)                    // single monotonic counter
{
    constexpr int T = 2048;
    constexpr int GBLK = 16;
    const int tid  = threadIdx.x;
    const int lane = tid & 63;
    const int w    = tid >> 6;
    const int gate = w & 3;
    const int ch   = w >> 2;                 // col-half 0/1
    const int quad = lane >> 4, l15 = lane & 15;
    const int col0 = blockIdx.x * 32;

    __shared__ __align__(16) float gl[4][32][34];  // padded: +2 breaks b-stride conflicts
    __shared__ int sBail;
    if (tid == 0) sBail = 0;  // ordered before first read by the t=0 gl barrier

    // ---- stage this wave's Wh slice into registers (once) ----
    short8 wfrag[16];
    {
        const short* wrow = (const short*)Wh
            + (size_t)(gate * 512 + col0 + ch * 16 + l15) * 512 + quad * 8;
        #pragma unroll
        for (int kk = 0; kk < 16; ++kk)
            wfrag[kk] = *(const short8*)(wrow + kk * 32);
    }

    // ---- elementwise ownership: thread -> (b, col, col+1) ----
    const int eb   = tid >> 4;               // 0..31
    const int ecol = (tid & 15) * 2;         // 0,2,..,30 (local col)
    const int ecg  = col0 + ecol;            // global h col

    const short* i2hs = (const short*)i2h;
    uint pf0, pf1, pf2, pf3;                 // i2h prefetch regs (4 gates x 2 cols)
    {
        const size_t base = (size_t)eb * 2048 + ecg;   // t = 0
        pf0 = *(const uint*)(i2hs + base);
        pf1 = *(const uint*)(i2hs + base + 512);
        pf2 = *(const uint*)(i2hs + base + 1024);
        pf3 = *(const uint*)(i2hs + base + 1536);
    }
    float cr0 = 0.f, cr1 = 0.f;              // c state, register-resident
    bool bail = false;

    for (int t = 0; t < T; ++t) {
        // ---- GEMM: gates += h_prev @ Wh^T (this wave's 16 cols) ----
        const short* hp = (const short*)((t & 1) ? hB : hA);
        f32x4 acc0 = {}, acc1 = {};
        const short* pa = hp + l15 * 512 + quad * 8;
        const short* pb = hp + (16 + l15) * 512 + quad * 8;
        #pragma unroll
        for (int kk = 0; kk < 16; ++kk) {
            const short8 a0 = *(const short8*)(pa + kk * 32);
            const short8 a1 = *(const short8*)(pb + kk * 32);
            acc0 = MFMA_BF16_16x16x32(a0, wfrag[kk], acc0);
            acc1 = MFMA_BF16_16x16x32(a1, wfrag[kk], acc1);
        }
        #pragma unroll
        for (int r = 0; r < 4; ++r) {
            gl[gate][quad * 4 + r][ch * 16 + l15]      = acc0[r];
            gl[gate][16 + quad * 4 + r][ch * 16 + l15] = acc1[r];
        }
        __syncthreads();

        // ---- elementwise: consume gl + prefetched i2h ----
        const float2 gi = *(const float2*)&gl[0][eb][ecol];
        const float2 gf = *(const float2*)&gl[1][eb][ecol];
        const float2 gg = *(const float2*)&gl[2][eb][ecol];
        const float2 go = *(const float2*)&gl[3][eb][ecol];
        const float iv0 = gi.x + bflo(pf0), iv1 = gi.y + bfhi(pf0);
        const float fv0 = gf.x + bflo(pf1), fv1 = gf.y + bfhi(pf1);
        const float gv0 = gg.x + bflo(pf2), gv1 = gg.y + bfhi(pf2);
        const float ov0 = go.x + bflo(pf3), ov1 = go.y + bfhi(pf3);

        // issue i2h prefetch for t+1 (hides HBM latency under math+barrier)
        {
            const int tn = (t + 1 < T) ? (t + 1) : t;
            const size_t nb = ((size_t)tn * 32 + eb) * 2048 + ecg;
            pf0 = *(const uint*)(i2hs + nb);
            pf1 = *(const uint*)(i2hs + nb + 512);
            pf2 = *(const uint*)(i2hs + nb + 1024);
            pf3 = *(const uint*)(i2hs + nb + 1536);
        }

        const float ig0 = 1.f / (1.f + __expf(-iv0));
        const float ig1 = 1.f / (1.f + __expf(-iv1));
        const float fg0 = 1.f / (1.f + __expf(-fv0));
        const float fg1 = 1.f / (1.f + __expf(-fv1));
        const float cg0 = 1.f - 2.f / (__expf(2.f * gv0) + 1.f);
        const float cg1 = 1.f - 2.f / (__expf(2.f * gv1) + 1.f);
        const float og0 = 1.f / (1.f + __expf(-ov0));
        const float og1 = 1.f / (1.f + __expf(-ov1));
        cr0 = fg0 * cr0 + ig0 * cg0;
        cr1 = fg1 * cr1 + ig1 * cg1;
        const float hn0 = og0 * (1.f - 2.f / (__expf(2.f * cr0) + 1.f));
        const float hn1 = og1 * (1.f - 2.f / (__expf(2.f * cr1) + 1.f));

        const uint hpk = (uint)(ushort)f2bf(hn0) | ((uint)(ushort)f2bf(hn1) << 16);
        short* hw = (short*)((t & 1) ? hA : hB);   // write buffer (other parity)
        *(uint*)(hw + eb * 512 + ecg) = hpk;
        if constexpr (std::is_same<YT, float>::value) {
            float2 yv; yv.x = hn0; yv.y = hn1;
            *(float2*)(y + (size_t)eb * (2048 * 512) + (size_t)t * 512 + ecg) = yv;
        } else {
            *(uint*)((short*)y + (size_t)eb * (2048 * 512) + (size_t)t * 512 + ecg) = hpk;
        }

        if (t == T - 1) break;                 // no barrier after final step

        // ---- device-scope step barrier (single spinner, hang-proof) ----
        __syncthreads();                       // all waves' stores drained (vmcnt 0)
        if (!bail) {
            if (tid == 0) {
                // RELEASE RMW: this block's h stores become agent-visible
                // before its arrival is observable.
                __hip_atomic_fetch_add(cnt, 1, __ATOMIC_RELEASE,
                                       __HIP_MEMORY_SCOPE_AGENT);
                const int target = GBLK * (t + 1);
                int iters = 0;
                while (__hip_atomic_load(cnt, __ATOMIC_RELAXED,
                                         __HIP_MEMORY_SCOPE_AGENT) < target) {
                    __builtin_amdgcn_s_sleep(1);
                    if (++iters > 2000000) { sBail = 1; break; }
                }
                // ACQUIRE: invalidate CU-shared L1 + XCD L2 before any wave
                // of this block reads the other blocks' h columns.
                __builtin_amdgcn_fence(__ATOMIC_ACQUIRE, "agent");
            }
            __syncthreads();                   // releases block; orders sBail
            if (sBail) bail = true;
        }
    }

    // final c (h already in hA: t=2047 wrote the 'a' buffer)
    c_out[eb * 512 + ecg]     = cr0;
    c_out[eb * 512 + ecg + 1] = cr1;
}

// ---------------------------------------------------------------------------
// Copy final h/c of both layers into d_out tail (fp32).
// Tail layout (fp32 elems, rel. to out+33554432):
//   h[0] at 0..16383, h[1] at 16384..32767, c[0] at 32768..49151, c[1] at 49152..
// ---------------------------------------------------------------------------
__global__ __launch_bounds__(256) void lstm_copy_finals(
    const __hip_bfloat16* __restrict__ h0, const __hip_bfloat16* __restrict__ h1,
    const float* __restrict__ c0, const float* __restrict__ c1,
    float* __restrict__ out)
{
    const int i = blockIdx.x * 256 + threadIdx.x;  // 0..16383
    out[i]         = __bfloat162float(h0[i]);
    out[16384 + i] = __bfloat162float(h1[i]);
    out[32768 + i] = c0[i];
    out[49152 + i] = c1[i];
}

extern "C" void kernel_launch(void* const* d_in, const int* in_sizes, int n_in,
                              void* d_out, int out_size, void* d_ws, size_t ws_size,
                              hipStream_t stream)
{
    const float* x   = (const float*)d_in[0];
    const float* Wi0 = (const float*)d_in[1];
    const float* bi0 = (const float*)d_in[2];
    const float* Wh0 = (const float*)d_in[3];
    const float* bh0 = (const float*)d_in[4];
    const float* Wi1 = (const float*)d_in[5];
    const float* bi1 = (const float*)d_in[6];
    const float* Wh1 = (const float*)d_in[7];
    const float* bh1 = (const float*)d_in[8];
    float* out = (float*)d_out;

    char* ws = (char*)d_ws;
    __hip_bfloat16* i2h  = (__hip_bfloat16*)(ws);
    __hip_bfloat16* y0   = (__hip_bfloat16*)(ws + 268435456ULL);
    __hip_bfloat16* Whb0 = (__hip_bfloat16*)(ws + 335544320ULL);
    __hip_bfloat16* Whb1 = (__hip_bfloat16*)(ws + 337641472ULL);
    __hip_bfloat16* h0a  = (__hip_bfloat16*)(ws + 339738624ULL);
    __hip_bfloat16* h0b  = (__hip_bfloat16*)(ws + 339771392ULL);
    __hip_bfloat16* h1a  = (__hip_bfloat16*)(ws + 339804160ULL);
    __hip_bfloat16* h1b  = (__hip_bfloat16*)(ws + 339836928ULL);
    float*          c0   = (float*)(ws + 339869696ULL);
    float*          c1   = (float*)(ws + 339935232ULL);

    // barrier counters live at the head of d_out's finals region; copy_finals
    // fully overwrites that region at the end of the launch sequence.
    int* cnts = (int*)((char*)d_out + 134217728ULL);

    // zero initial h state (ws is poisoned 0xAA before every call) + counters
    hipMemsetAsync(h0a, 0, 32768, stream);
    hipMemsetAsync(h1a, 0, 32768, stream);
    hipMemsetAsync(cnts, 0, 8, stream);

    // pre-convert Wh weights to bf16 (1048576 elems each = 262144 float4s)
    cvt_f32_bf16<<<1024, 256, 0, stream>>>(Wh0, Whb0);
    cvt_f32_bf16<<<1024, 256, 0, stream>>>(Wh1, Whb1);

    const dim3 ggrid(16, 512);  // N/128, M/128

    // ---- layer 0 ----
    lstm_gemm_i2h<float><<<ggrid, 256, 0, stream>>>(x, Wi0, bi0, bh0, i2h);
    lstm_persist<__hip_bfloat16><<<16, 512, 0, stream>>>(
        i2h, Whb0, h0a, h0b, c0, y0, cnts + 0);

    // ---- layer 1 ----
    lstm_gemm_i2h<__hip_bfloat16><<<ggrid, 256, 0, stream>>>(y0, Wi1, bi1, bh1, i2h);
    lstm_persist<float><<<16, 512, 0, stream>>>(
        i2h, Whb1, h1a, h1b, c1, out, cnts + 1);

    // final (h, c): t=2047 wrote the 'a' buffers
    lstm_copy_finals<<<64, 256, 0, stream>>>(h0a, h1a, c0, c1, out + 33554432ULL);
}

// Round 4
// 16000.027 us; speedup vs baseline: 2.5074x; 2.5074x over previous
//
#include <hip/hip_runtime.h>
#include <hip/hip_bf16.h>
#include <cstdint>
#include <cstddef>
#include <type_traits>

// Problem: 2-layer LSTM, B=32, T=2048, D=H=512, 4H=2048.
//
// ws layout (bytes):
//   i2h  [T][4][16][32][32] bf16 (t, gate, colblk, b, col) : off 0, size 268435456
//   y0   [B][T][H]  bf16 : off 268435456,  size 67108864
//   Whb0 [2048][512] bf16: off 335544320,  size 2097152
//   Whb1 [2048][512] bf16: off 337641472,  size 2097152
//   h0a  [B][H]     bf16 : off 339738624,  size 32768
//   h0b                  : off 339771392
//   h1a                  : off 339804160
//   h1b                  : off 339836928
//   c0   [B][H]     f32  : off 339869696,  size 65536
//   c1                   : off 339935232
// Barrier counters live in d_out's finals region (overwritten by copy_finals).

typedef __attribute__((ext_vector_type(8))) short short8;   // 8 x bf16
typedef __attribute__((ext_vector_type(4))) short short4v;  // 4 x bf16
typedef __attribute__((ext_vector_type(4))) float f32x4;
typedef __attribute__((ext_vector_type(4))) int int4v;

#define MFMA_BF16_16x16x32(A_, B_, C_) \
    __builtin_amdgcn_mfma_f32_16x16x32_bf16(A_, B_, C_, 0, 0, 0)

__device__ __forceinline__ short f2bf(float f) {
    __hip_bfloat16 b = __float2bfloat16(f);
    return *reinterpret_cast<short*>(&b);
}
__device__ __forceinline__ float bflo(uint u) {
    union { uint i; float f; } x; x.i = u << 16; return x.f;
}
__device__ __forceinline__ float bfhi(uint u) {
    union { uint i; float f; } x; x.i = u & 0xffff0000u; return x.f;
}

// ---------------------------------------------------------------------------
// fp32 -> bf16 elementwise convert (for Wh weights), one float4 per thread.
// ---------------------------------------------------------------------------
__global__ __launch_bounds__(256) void cvt_f32_bf16(
    const float* __restrict__ in, __hip_bfloat16* __restrict__ outp)
{
    const int i = blockIdx.x * 256 + threadIdx.x;
    const float4 v = ((const float4*)in)[i];
    short4v o;
    o[0] = f2bf(v.x); o[1] = f2bf(v.y); o[2] = f2bf(v.z); o[3] = f2bf(v.w);
    ((short4v*)outp)[i] = o;
}

// ---------------------------------------------------------------------------
// i2h GEMM: C[m][n] = sum_k A[m][k] * W[n][k] + bi[n] + bh[n]
// A: [M=65536, K=512] row-major, dtype AT (float for layer0, bf16 for layer1)
//    (m = b*2048 + t)
// W: [N=2048, K=512] fp32 row-major, converted to bf16 during staging
// out: PERMUTED [T][gate][colblk j][b][32] bf16 — so each persist block reads
//      full 128-B lines (fixes the 2x HBM over-fetch seen in round-2 rocprof).
// 128x128 tile, BK=32, 256 threads (4 waves, 2x2 wave quadrants of 64x64)
// ---------------------------------------------------------------------------
template <typename AT>
__global__ __launch_bounds__(256) void lstm_gemm_i2h(
    const AT* __restrict__ A,
    const float* __restrict__ W,
    const float* __restrict__ bi,
    const float* __restrict__ bh,
    __hip_bfloat16* __restrict__ out)
{
    constexpr int K = 512;
    const int tid  = threadIdx.x;
    const int lane = tid & 63;
    const int w    = tid >> 6;
    const int wm   = w >> 1, wn = w & 1;
    const int quad = lane >> 4, l15 = lane & 15;
    const int m0 = blockIdx.y * 128;
    const int n0 = blockIdx.x * 128;

    __shared__ __align__(16) short sA[128 * 32];
    __shared__ __align__(16) short sB[128 * 32];

    f32x4 acc[4][4] = {};

    // fp32 staging coords: 2 threads per row, 16 floats each
    const int frow = tid >> 1;         // 0..127
    const int fcol = (tid & 1) * 16;   // 0 or 16
    // bf16 staging coords: 4 threads per row, 8 shorts each, 2 rows/thread
    const int brow = tid >> 2;         // 0..63
    const int bcol = (tid & 3) * 8;    // 0,8,16,24

    for (int k0 = 0; k0 < K; k0 += 32) {
        __syncthreads();
        // ---- stage A ----
        if constexpr (std::is_same<AT, float>::value) {
            const float* ap = A + (size_t)(m0 + frow) * K + k0 + fcol;
            float4 v0 = ((const float4*)ap)[0];
            float4 v1 = ((const float4*)ap)[1];
            float4 v2 = ((const float4*)ap)[2];
            float4 v3 = ((const float4*)ap)[3];
            short8 lo, hi;
            lo[0]=f2bf(v0.x); lo[1]=f2bf(v0.y); lo[2]=f2bf(v0.z); lo[3]=f2bf(v0.w);
            lo[4]=f2bf(v1.x); lo[5]=f2bf(v1.y); lo[6]=f2bf(v1.z); lo[7]=f2bf(v1.w);
            hi[0]=f2bf(v2.x); hi[1]=f2bf(v2.y); hi[2]=f2bf(v2.z); hi[3]=f2bf(v2.w);
            hi[4]=f2bf(v3.x); hi[5]=f2bf(v3.y); hi[6]=f2bf(v3.z); hi[7]=f2bf(v3.w);
            *(short8*)&sA[frow * 32 + fcol]     = lo;
            *(short8*)&sA[frow * 32 + fcol + 8] = hi;
        } else {
            const int4v a0 = *(const int4v*)((const short*)A + (size_t)(m0 + brow) * K + k0 + bcol);
            const int4v a1 = *(const int4v*)((const short*)A + (size_t)(m0 + brow + 64) * K + k0 + bcol);
            *(int4v*)&sA[brow * 32 + bcol]        = a0;
            *(int4v*)&sA[(brow + 64) * 32 + bcol] = a1;
        }
        // ---- stage W (always fp32 -> bf16) ----
        {
            const float* wp = W + (size_t)(n0 + frow) * K + k0 + fcol;
            float4 v0 = ((const float4*)wp)[0];
            float4 v1 = ((const float4*)wp)[1];
            float4 v2 = ((const float4*)wp)[2];
            float4 v3 = ((const float4*)wp)[3];
            short8 lo, hi;
            lo[0]=f2bf(v0.x); lo[1]=f2bf(v0.y); lo[2]=f2bf(v0.z); lo[3]=f2bf(v0.w);
            lo[4]=f2bf(v1.x); lo[5]=f2bf(v1.y); lo[6]=f2bf(v1.z); lo[7]=f2bf(v1.w);
            hi[0]=f2bf(v2.x); hi[1]=f2bf(v2.y); hi[2]=f2bf(v2.z); hi[3]=f2bf(v2.w);
            hi[4]=f2bf(v3.x); hi[5]=f2bf(v3.y); hi[6]=f2bf(v3.z); hi[7]=f2bf(v3.w);
            *(short8*)&sB[frow * 32 + fcol]     = lo;
            *(short8*)&sB[frow * 32 + fcol + 8] = hi;
        }
        __syncthreads();

        short8 aF[4], bF[4];
        #pragma unroll
        for (int i = 0; i < 4; ++i) {
            aF[i] = *(const short8*)&sA[(wm * 64 + i * 16 + l15) * 32 + quad * 8];
            bF[i] = *(const short8*)&sB[(wn * 64 + i * 16 + l15) * 32 + quad * 8];
        }
        #pragma unroll
        for (int mi = 0; mi < 4; ++mi)
            #pragma unroll
            for (int ni = 0; ni < 4; ++ni)
                acc[mi][ni] = MFMA_BF16_16x16x32(aF[mi], bF[ni], acc[mi][ni]);
    }

    // epilogue: D row = quad*4 + r (m), col = l15 (n); scatter into permuted
    // i2h layout [t][g][j][b][c2]
    #pragma unroll
    for (int ni = 0; ni < 4; ++ni) {
        const int n = n0 + wn * 64 + ni * 16 + l15;
        const float bias = bi[n] + bh[n];
        const int g  = n >> 9;
        const int j  = (n >> 5) & 15;
        const int c2 = n & 31;
        #pragma unroll
        for (int mi = 0; mi < 4; ++mi) {
            #pragma unroll
            for (int r = 0; r < 4; ++r) {
                const int m = m0 + wm * 64 + mi * 16 + quad * 4 + r;
                const int b = m >> 11;      // m / 2048
                const int t = m & 2047;     // m % 2048
                out[((((size_t)t * 4 + g) * 16 + j) * 32 + b) * 32 + c2] =
                    __float2bfloat16(acc[mi][ni][r] + bias);
            }
        }
    }
}

// ---------------------------------------------------------------------------
// Persistent recurrence kernel: all 2048 timesteps in ONE launch.
//
// Grid: 16 blocks x 512 threads (8 waves). Block j owns h-columns
// [j*32, j*32+32) for ALL 4 gates (= 128 rows of Wh, register-resident).
//
// FENCE-FREE cross-block h exchange, race-hardened (round-3 lesson):
//   - h stores: WITH-RETURN atomic exchange, agent scope. A returning RMW is
//     performed AT the LLC and its vmcnt ack is the LLC response — so the
//     pre-barrier vmcnt(0) drain PROVES h is in the LLC before the arrival
//     add issues. (Round 3 used relaxed atomic stores; their ack can be
//     posted at the XCD boundary -> counter visible before data -> stale h
//     on some replays: post-timing absmax 0.19.)
//   - h reads : cache-BYPASS loads (global_load_dwordx4 sc0 sc1, straight
//     from LLC), staged once per block into swizzled LDS.
//   - barrier : __syncthreads (drains RMW acks) -> tid0 relaxed fetch_add ->
//     spin relaxed loads -> __syncthreads. No wbl2 / no cache invalidates.
//     Spin is iteration-capped (bail flag) -> hang-proof.
// 16 blocks on 256 CUs -> co-residency guaranteed.
// ---------------------------------------------------------------------------
template <typename YT>
__global__ __launch_bounds__(512, 2) void lstm_persist(
    const __hip_bfloat16* __restrict__ i2h,   // [T][4][16][32][32] permuted
    const __hip_bfloat16* __restrict__ Wh,    // [2048][512] bf16
    __hip_bfloat16* __restrict__ hA,          // [32][512] read at even t
    __hip_bfloat16* __restrict__ hB,          // [32][512] read at odd t
    float* __restrict__ c_out,                // [32][512] written once at end
    YT* __restrict__ y,                       // [B][T][H]
    int* __restrict__ cnt)                    // single monotonic counter
{
    constexpr int T = 2048;
    constexpr int GBLK = 16;
    const int tid  = threadIdx.x;
    const int lane = tid & 63;
    const int w    = tid >> 6;
    const int gate = w & 3;
    const int ch   = w >> 2;                 // col-half 0/1
    const int quad = lane >> 4, l15 = lane & 15;
    const int bx   = blockIdx.x;
    const int col0 = bx * 32;

    // h tile staged per step: [32 rows][64 slots of 16B], slot ^= (row&7)
    __shared__ __align__(16) short hs[32 * 512];
    __shared__ __align__(16) float gl[4][32][34];  // padded
    __shared__ int sBail;
    if (tid == 0) sBail = 0;

    // ---- stage this wave's Wh slice into registers (once) ----
    short8 wfrag[16];
    {
        const short* wrow = (const short*)Wh
            + (size_t)(gate * 512 + col0 + ch * 16 + l15) * 512 + quad * 8;
        #pragma unroll
        for (int kk = 0; kk < 16; ++kk)
            wfrag[kk] = *(const short8*)(wrow + kk * 32);
    }

    // ---- elementwise ownership: thread -> (b, col, col+1) ----
    const int eb   = tid >> 4;               // 0..31
    const int ecol = (tid & 15) * 2;         // 0,2,..,30 (local col)
    const int ecg  = col0 + ecol;            // global h col

    // ---- h staging ownership: thread -> (row, 4 slots) ----
    const int sr = tid >> 4;                 // 0..31
    const int ss = tid & 15;                 // base slot

    const short* i2hs = (const short*)i2h;
    uint pf0, pf1, pf2, pf3;                 // i2h prefetch regs (4 gates x 2 cols)
    {
        const size_t tb = (size_t)bx * 1024 + eb * 32 + ecol;   // t = 0
        pf0 = *(const uint*)(i2hs + tb);
        pf1 = *(const uint*)(i2hs + tb + 16384);
        pf2 = *(const uint*)(i2hs + tb + 32768);
        pf3 = *(const uint*)(i2hs + tb + 49152);
    }
    float cr0 = 0.f, cr1 = 0.f;              // c state, register-resident
    bool bail = false;

    for (int t = 0; t < T; ++t) {
        // ---- stage h[t] -> LDS (bypass L1/L2, fresh from LLC) ----
        {
            const short* hp = (const short*)((t & 1) ? hB : hA);
            const short* p0 = hp + sr * 512 + (ss +  0) * 8;
            const short* p1 = hp + sr * 512 + (ss + 16) * 8;
            const short* p2 = hp + sr * 512 + (ss + 32) * 8;
            const short* p3 = hp + sr * 512 + (ss + 48) * 8;
            int4v v0, v1, v2, v3;
            asm volatile("global_load_dwordx4 %0, %1, off sc0 sc1" : "=v"(v0) : "v"(p0));
            asm volatile("global_load_dwordx4 %0, %1, off sc0 sc1" : "=v"(v1) : "v"(p1));
            asm volatile("global_load_dwordx4 %0, %1, off sc0 sc1" : "=v"(v2) : "v"(p2));
            asm volatile("global_load_dwordx4 %0, %1, off sc0 sc1" : "=v"(v3) : "v"(p3));
            asm volatile("s_waitcnt vmcnt(0)" ::: "memory");
            *(int4v*)&hs[((sr * 64 + ss +  0) ^ (sr & 7)) * 8] = v0;
            *(int4v*)&hs[((sr * 64 + ss + 16) ^ (sr & 7)) * 8] = v1;
            *(int4v*)&hs[((sr * 64 + ss + 32) ^ (sr & 7)) * 8] = v2;
            *(int4v*)&hs[((sr * 64 + ss + 48) ^ (sr & 7)) * 8] = v3;
        }
        __syncthreads();

        // ---- GEMM: gates += h_prev @ Wh^T (this wave's 16 cols) ----
        f32x4 acc0 = {}, acc1 = {};
        #pragma unroll
        for (int kk = 0; kk < 16; ++kk) {
            const short8 a0 = *(const short8*)
                &hs[((l15 * 64 + quad + kk * 4) ^ (l15 & 7)) * 8];
            const short8 a1 = *(const short8*)
                &hs[(((16 + l15) * 64 + quad + kk * 4) ^ (l15 & 7)) * 8];
            acc0 = MFMA_BF16_16x16x32(a0, wfrag[kk], acc0);
            acc1 = MFMA_BF16_16x16x32(a1, wfrag[kk], acc1);
        }
        #pragma unroll
        for (int r = 0; r < 4; ++r) {
            gl[gate][quad * 4 + r][ch * 16 + l15]      = acc0[r];
            gl[gate][16 + quad * 4 + r][ch * 16 + l15] = acc1[r];
        }
        __syncthreads();

        // ---- elementwise: consume gl + prefetched i2h ----
        const float2 gi = *(const float2*)&gl[0][eb][ecol];
        const float2 gf = *(const float2*)&gl[1][eb][ecol];
        const float2 gg = *(const float2*)&gl[2][eb][ecol];
        const float2 go = *(const float2*)&gl[3][eb][ecol];
        const float iv0 = gi.x + bflo(pf0), iv1 = gi.y + bfhi(pf0);
        const float fv0 = gf.x + bflo(pf1), fv1 = gf.y + bfhi(pf1);
        const float gv0 = gg.x + bflo(pf2), gv1 = gg.y + bfhi(pf2);
        const float ov0 = go.x + bflo(pf3), ov1 = go.y + bfhi(pf3);

        // issue i2h prefetch for t+1 (hides HBM latency under math+barrier)
        {
            const int tn = (t + 1 < T) ? (t + 1) : t;
            const size_t nb = (size_t)tn * 65536 + (size_t)bx * 1024 + eb * 32 + ecol;
            pf0 = *(const uint*)(i2hs + nb);
            pf1 = *(const uint*)(i2hs + nb + 16384);
            pf2 = *(const uint*)(i2hs + nb + 32768);
            pf3 = *(const uint*)(i2hs + nb + 49152);
        }

        const float ig0 = 1.f / (1.f + __expf(-iv0));
        const float ig1 = 1.f / (1.f + __expf(-iv1));
        const float fg0 = 1.f / (1.f + __expf(-fv0));
        const float fg1 = 1.f / (1.f + __expf(-fv1));
        const float cg0 = 1.f - 2.f / (__expf(2.f * gv0) + 1.f);
        const float cg1 = 1.f - 2.f / (__expf(2.f * gv1) + 1.f);
        const float og0 = 1.f / (1.f + __expf(-ov0));
        const float og1 = 1.f / (1.f + __expf(-ov1));
        cr0 = fg0 * cr0 + ig0 * cg0;
        cr1 = fg1 * cr1 + ig1 * cg1;
        const float hn0 = og0 * (1.f - 2.f / (__expf(2.f * cr0) + 1.f));
        const float hn1 = og1 * (1.f - 2.f / (__expf(2.f * cr1) + 1.f));

        const uint hpk = (uint)(ushort)f2bf(hn0) | ((uint)(ushort)f2bf(hn1) << 16);
        short* hw = (short*)((t & 1) ? hA : hB);   // write buffer (other parity)
        // WITH-RETURN exchange: executed at the LLC, vmcnt ack = LLC response.
        // After the pre-barrier vmcnt(0) drain, h is provably LLC-visible.
        {
            uint old = __hip_atomic_exchange((uint*)(hw + eb * 512 + ecg), hpk,
                                             __ATOMIC_RELAXED,
                                             __HIP_MEMORY_SCOPE_AGENT);
            asm volatile("" : : "v"(old));     // keep the returning form
        }
        if constexpr (std::is_same<YT, float>::value) {
            float2 yv; yv.x = hn0; yv.y = hn1;
            *(float2*)(y + (size_t)eb * (2048 * 512) + (size_t)t * 512 + ecg) = yv;
        } else {
            *(uint*)((short*)y + (size_t)eb * (2048 * 512) + (size_t)t * 512 + ecg) = hpk;
        }

        if (t == T - 1) break;                 // no barrier after final step

        // ---- fence-free device barrier (single spinner, hang-proof) ----
        __syncthreads();                       // all waves' RMW acks drained (vmcnt 0)
        if (!bail) {
            if (tid == 0) {
                __hip_atomic_fetch_add(cnt, 1, __ATOMIC_RELAXED,
                                       __HIP_MEMORY_SCOPE_AGENT);
                const int target = GBLK * (t + 1);
                int iters = 0;
                while (__hip_atomic_load(cnt, __ATOMIC_RELAXED,
                                         __HIP_MEMORY_SCOPE_AGENT) < target) {
                    if (++iters > 1000000) { sBail = 1; break; }
                }
            }
            __syncthreads();                   // releases block; orders sBail
            if (sBail) bail = true;
        }
    }

    // final c (h already in hA: t=2047 wrote the 'a' buffer)
    c_out[eb * 512 + ecg]     = cr0;
    c_out[eb * 512 + ecg + 1] = cr1;
}

// ---------------------------------------------------------------------------
// Copy final h/c of both layers into d_out tail (fp32).
// Tail layout (fp32 elems, rel. to out+33554432):
//   h[0] at 0..16383, h[1] at 16384..32767, c[0] at 32768..49151, c[1] at 49152..
// ---------------------------------------------------------------------------
__global__ __launch_bounds__(256) void lstm_copy_finals(
    const __hip_bfloat16* __restrict__ h0, const __hip_bfloat16* __restrict__ h1,
    const float* __restrict__ c0, const float* __restrict__ c1,
    float* __restrict__ out)
{
    const int i = blockIdx.x * 256 + threadIdx.x;  // 0..16383
    out[i]         = __bfloat162float(h0[i]);
    out[16384 + i] = __bfloat162float(h1[i]);
    out[32768 + i] = c0[i];
    out[49152 + i] = c1[i];
}

extern "C" void kernel_launch(void* const* d_in, const int* in_sizes, int n_in,
                              void* d_out, int out_size, void* d_ws, size_t ws_size,
                              hipStream_t stream)
{
    const float* x   = (const float*)d_in[0];
    const float* Wi0 = (const float*)d_in[1];
    const float* bi0 = (const float*)d_in[2];
    const float* Wh0 = (const float*)d_in[3];
    const float* bh0 = (const float*)d_in[4];
    const float* Wi1 = (const float*)d_in[5];
    const float* bi1 = (const float*)d_in[6];
    const float* Wh1 = (const float*)d_in[7];
    const float* bh1 = (const float*)d_in[8];
    float* out = (float*)d_out;

    char* ws = (char*)d_ws;
    __hip_bfloat16* i2h  = (__hip_bfloat16*)(ws);
    __hip_bfloat16* y0   = (__hip_bfloat16*)(ws + 268435456ULL);
    __hip_bfloat16* Whb0 = (__hip_bfloat16*)(ws + 335544320ULL);
    __hip_bfloat16* Whb1 = (__hip_bfloat16*)(ws + 337641472ULL);
    __hip_bfloat16* h0a  = (__hip_bfloat16*)(ws + 339738624ULL);
    __hip_bfloat16* h0b  = (__hip_bfloat16*)(ws + 339771392ULL);
    __hip_bfloat16* h1a  = (__hip_bfloat16*)(ws + 339804160ULL);
    __hip_bfloat16* h1b  = (__hip_bfloat16*)(ws + 339836928ULL);
    float*          c0   = (float*)(ws + 339869696ULL);
    float*          c1   = (float*)(ws + 339935232ULL);

    // barrier counters live at the head of d_out's finals region; copy_finals
    // fully overwrites that region at the end of the launch sequence.
    int* cnts = (int*)((char*)d_out + 134217728ULL);

    // zero initial h state (ws is poisoned 0xAA before every call) + counters
    hipMemsetAsync(h0a, 0, 32768, stream);
    hipMemsetAsync(h1a, 0, 32768, stream);
    hipMemsetAsync(cnts, 0, 8, stream);

    // pre-convert Wh weights to bf16 (1048576 elems each = 262144 float4s)
    cvt_f32_bf16<<<1024, 256, 0, stream>>>(Wh0, Whb0);
    cvt_f32_bf16<<<1024, 256, 0, stream>>>(Wh1, Whb1);

    const dim3 ggrid(16, 512);  // N/128, M/128

    // ---- layer 0 ----
    lstm_gemm_i2h<float><<<ggrid, 256, 0, stream>>>(x, Wi0, bi0, bh0, i2h);
    lstm_persist<__hip_bfloat16><<<16, 512, 0, stream>>>(
        i2h, Whb0, h0a, h0b, c0, y0, cnts + 0);

    // ---- layer 1 ----
    lstm_gemm_i2h<__hip_bfloat16><<<ggrid, 256, 0, stream>>>(y0, Wi1, bi1, bh1, i2h);
    lstm_persist<float><<<16, 512, 0, stream>>>(
        i2h, Whb1, h1a, h1b, c1, out, cnts + 1);

    // final (h, c): t=2047 wrote the 'a' buffers
    lstm_copy_finals<<<64, 256, 0, stream>>>(h0a, h1a, c0, c1, out + 33554432ULL);
}

// Round 5
// 13893.179 us; speedup vs baseline: 2.8876x; 1.1516x over previous
//
#include <hip/hip_runtime.h>
#include <hip/hip_bf16.h>
#include <cstdint>
#include <cstddef>

// Problem: 2-layer LSTM, B=32, T=2048, D=H=512, 4H=2048.
//
// Structure (round 5): layer-0 i2h precomputed by one big GEMM; BOTH LSTM
// recurrences run in ONE persistent kernel as a 1-step-lag software pipeline:
//   blocks  0..15 : layer 0, step t = r      (reads i2h0[t], h0; writes y0[t], h0')
//   blocks 16..31 : layer 1, step t = r - 1  (reads y0[t], h1; computes i2h1 on
//                                             the fly via K=1024 GEMM; writes y1, h1')
// One device barrier per round (2048 rounds) instead of per layer per step.
//
// ws layout (bytes):
//   i2h  [T][4][16][32][32] bf16 : off 0,          size 268435456
//   y0   [B][T][H]  bf16        : off 268435456,   size 67108864
//   h0a  [32][512] bf16         : off 335544320,   size 32768
//   h0b                         : off 335577088
//   h1a                         : off 335609856
//   h1b                         : off 335642624
//   c0   [32][512] f32          : off 335675392,   size 65536
//   c1                          : off 335740928
// Barrier counter lives in d_out's finals region (overwritten by copy_finals).

typedef __attribute__((ext_vector_type(8))) short short8;   // 8 x bf16
typedef __attribute__((ext_vector_type(4))) short short4v;  // 4 x bf16
typedef __attribute__((ext_vector_type(4))) float f32x4;
typedef __attribute__((ext_vector_type(4))) int int4v;

#define MFMA_BF16_16x16x32(A_, B_, C_) \
    __builtin_amdgcn_mfma_f32_16x16x32_bf16(A_, B_, C_, 0, 0, 0)

__device__ __forceinline__ short f2bf(float f) {
    __hip_bfloat16 b = __float2bfloat16(f);
    return *reinterpret_cast<short*>(&b);
}
__device__ __forceinline__ float bflo(uint u) {
    union { uint i; float f; } x; x.i = u << 16; return x.f;
}
__device__ __forceinline__ float bfhi(uint u) {
    union { uint i; float f; } x; x.i = u & 0xffff0000u; return x.f;
}
__device__ __forceinline__ short8 cvt8(const float* __restrict__ p) {
    const float4 v0 = ((const float4*)p)[0];
    const float4 v1 = ((const float4*)p)[1];
    short8 r;
    r[0]=f2bf(v0.x); r[1]=f2bf(v0.y); r[2]=f2bf(v0.z); r[3]=f2bf(v0.w);
    r[4]=f2bf(v1.x); r[5]=f2bf(v1.y); r[6]=f2bf(v1.z); r[7]=f2bf(v1.w);
    return r;
}

// ---------------------------------------------------------------------------
// i2h GEMM (layer 0 only): C[m][n] = sum_k x[m][k] * Wi0[n][k] + bi0[n]+bh0[n]
// out: PERMUTED [T][gate][colblk j][b][32] bf16 so each persist block reads
// full 128-B lines.
// ---------------------------------------------------------------------------
__global__ __launch_bounds__(256) void lstm_gemm_i2h(
    const float* __restrict__ A,
    const float* __restrict__ W,
    const float* __restrict__ bi,
    const float* __restrict__ bh,
    __hip_bfloat16* __restrict__ out)
{
    constexpr int K = 512;
    const int tid  = threadIdx.x;
    const int lane = tid & 63;
    const int w    = tid >> 6;
    const int wm   = w >> 1, wn = w & 1;
    const int quad = lane >> 4, l15 = lane & 15;
    const int m0 = blockIdx.y * 128;
    const int n0 = blockIdx.x * 128;

    __shared__ __align__(16) short sA[128 * 32];
    __shared__ __align__(16) short sB[128 * 32];

    f32x4 acc[4][4] = {};

    const int frow = tid >> 1;         // 0..127
    const int fcol = (tid & 1) * 16;   // 0 or 16

    for (int k0 = 0; k0 < K; k0 += 32) {
        __syncthreads();
        {
            const float* ap = A + (size_t)(m0 + frow) * K + k0 + fcol;
            float4 v0 = ((const float4*)ap)[0];
            float4 v1 = ((const float4*)ap)[1];
            float4 v2 = ((const float4*)ap)[2];
            float4 v3 = ((const float4*)ap)[3];
            short8 lo, hi;
            lo[0]=f2bf(v0.x); lo[1]=f2bf(v0.y); lo[2]=f2bf(v0.z); lo[3]=f2bf(v0.w);
            lo[4]=f2bf(v1.x); lo[5]=f2bf(v1.y); lo[6]=f2bf(v1.z); lo[7]=f2bf(v1.w);
            hi[0]=f2bf(v2.x); hi[1]=f2bf(v2.y); hi[2]=f2bf(v2.z); hi[3]=f2bf(v2.w);
            hi[4]=f2bf(v3.x); hi[5]=f2bf(v3.y); hi[6]=f2bf(v3.z); hi[7]=f2bf(v3.w);
            *(short8*)&sA[frow * 32 + fcol]     = lo;
            *(short8*)&sA[frow * 32 + fcol + 8] = hi;
        }
        {
            const float* wp = W + (size_t)(n0 + frow) * K + k0 + fcol;
            float4 v0 = ((const float4*)wp)[0];
            float4 v1 = ((const float4*)wp)[1];
            float4 v2 = ((const float4*)wp)[2];
            float4 v3 = ((const float4*)wp)[3];
            short8 lo, hi;
            lo[0]=f2bf(v0.x); lo[1]=f2bf(v0.y); lo[2]=f2bf(v0.z); lo[3]=f2bf(v0.w);
            lo[4]=f2bf(v1.x); lo[5]=f2bf(v1.y); lo[6]=f2bf(v1.z); lo[7]=f2bf(v1.w);
            hi[0]=f2bf(v2.x); hi[1]=f2bf(v2.y); hi[2]=f2bf(v2.z); hi[3]=f2bf(v2.w);
            hi[4]=f2bf(v3.x); hi[5]=f2bf(v3.y); hi[6]=f2bf(v3.z); hi[7]=f2bf(v3.w);
            *(short8*)&sB[frow * 32 + fcol]     = lo;
            *(short8*)&sB[frow * 32 + fcol + 8] = hi;
        }
        __syncthreads();

        short8 aF[4], bF[4];
        #pragma unroll
        for (int i = 0; i < 4; ++i) {
            aF[i] = *(const short8*)&sA[(wm * 64 + i * 16 + l15) * 32 + quad * 8];
            bF[i] = *(const short8*)&sB[(wn * 64 + i * 16 + l15) * 32 + quad * 8];
        }
        #pragma unroll
        for (int mi = 0; mi < 4; ++mi)
            #pragma unroll
            for (int ni = 0; ni < 4; ++ni)
                acc[mi][ni] = MFMA_BF16_16x16x32(aF[mi], bF[ni], acc[mi][ni]);
    }

    // epilogue: scatter into permuted i2h layout [t][g][j][b][c2]
    #pragma unroll
    for (int ni = 0; ni < 4; ++ni) {
        const int n = n0 + wn * 64 + ni * 16 + l15;
        const float bias = bi[n] + bh[n];
        const int g  = n >> 9;
        const int j  = (n >> 5) & 15;
        const int c2 = n & 31;
        #pragma unroll
        for (int mi = 0; mi < 4; ++mi) {
            #pragma unroll
            for (int r = 0; r < 4; ++r) {
                const int m = m0 + wm * 64 + mi * 16 + quad * 4 + r;
                const int b = m >> 11;      // m / 2048
                const int t = m & 2047;     // m % 2048
                out[((((size_t)t * 4 + g) * 16 + j) * 32 + b) * 32 + c2] =
                    __float2bfloat16(acc[mi][ni][r] + bias);
            }
        }
    }
}

// ---------------------------------------------------------------------------
// Fused 2-layer persistent recurrence (1-step-lag pipeline).
// 32 blocks x 512 threads. Block j (of its layer) owns h-cols [j*32, j*32+32)
// for all 4 gates. Weights register-resident (L0: Wh0 16xshort8; L1: Wi1+Wh1
// 32xshort8 = K1024 GEMM, i2h1 computed on the fly from y0[t]).
//
// Cross-block data protocol (verified in round 4):
//   writes: WITH-RETURN atomic exchange, agent scope (executed at LLC; vmcnt
//           ack = LLC response, so the pre-barrier vmcnt(0) drain proves
//           LLC visibility). Applied to h0, h1, AND y0 (consumed by L1).
//   reads : cache-bypass global_load_dwordx4 sc0 sc1, staged into swizzled LDS.
//   barrier: __syncthreads -> tid0 relaxed fetch_add -> spin relaxed loads
//            (iteration-capped bail => hang-proof) -> __syncthreads.
// ---------------------------------------------------------------------------
__global__ __launch_bounds__(512, 1) void lstm_fused(
    const __hip_bfloat16* __restrict__ i2h,   // [T][4][16][32][32] permuted
    const float* __restrict__ Wh0,            // [2048][512] f32
    const float* __restrict__ Wi1,            // [2048][512] f32
    const float* __restrict__ Wh1,            // [2048][512] f32
    const float* __restrict__ bi1,
    const float* __restrict__ bh1,
    __hip_bfloat16* __restrict__ h0A, __hip_bfloat16* __restrict__ h0B,
    __hip_bfloat16* __restrict__ h1A, __hip_bfloat16* __restrict__ h1B,
    __hip_bfloat16* __restrict__ y0,          // [B][T][H] bf16 (L0 out, L1 in)
    float* __restrict__ y1,                   // [B][T][H] f32 (d_out)
    float* __restrict__ c0o, float* __restrict__ c1o,
    int* __restrict__ cnt)
{
    constexpr int T  = 2048;
    constexpr int NB = 32;
    const int tid  = threadIdx.x;
    const int lane = tid & 63;
    const int w    = tid >> 6;
    const int gate = w & 3;
    const int ch   = w >> 2;
    const int quad = lane >> 4, l15 = lane & 15;
    const bool isL1 = blockIdx.x >= 16;
    const int bx   = blockIdx.x & 15;
    const int col0 = bx * 32;

    // staged operand rows: [64 rows][64 slots of 16B], slot ^= (row&7).
    // L0 uses rows 0..31 (h0). L1: rows 0..31 = y0[t], rows 32..63 = h1.
    __shared__ __align__(16) short hs[64 * 512];
    __shared__ __align__(16) float gl[4][32][34];
    __shared__ int sBail;
    if (tid == 0) sBail = 0;

    // ---- weights -> registers (fp32 -> bf16 inline, once) ----
    short8 wf[32];
    {
        const int wrow = gate * 512 + col0 + ch * 16 + l15;
        if (!isL1) {
            const float* p = Wh0 + (size_t)wrow * 512 + quad * 8;
            #pragma unroll
            for (int kk = 0; kk < 16; ++kk) wf[kk] = cvt8(p + kk * 32);
            #pragma unroll
            for (int kk = 16; kk < 32; ++kk) wf[kk] = wf[0]; // unused, keep defined
        } else {
            const float* pi = Wi1 + (size_t)wrow * 512 + quad * 8;
            const float* ph = Wh1 + (size_t)wrow * 512 + quad * 8;
            #pragma unroll
            for (int kk = 0; kk < 16; ++kk) wf[kk] = cvt8(pi + kk * 32);
            #pragma unroll
            for (int kk = 0; kk < 16; ++kk) wf[16 + kk] = cvt8(ph + kk * 32);
        }
    }

    // ---- elementwise ownership: thread -> (b, col, col+1) ----
    const int eb   = tid >> 4;
    const int ecol = (tid & 15) * 2;
    const int ecg  = col0 + ecol;

    // L1 bias (folded at elementwise time; L0 has bias in i2h)
    float bI0=0,bI1=0,bF0=0,bF1=0,bG0=0,bG1=0,bO0=0,bO1=0;
    if (isL1) {
        bI0 = bi1[ecg]            + bh1[ecg];
        bI1 = bi1[ecg + 1]        + bh1[ecg + 1];
        bF0 = bi1[512 + ecg]      + bh1[512 + ecg];
        bF1 = bi1[512 + ecg + 1]  + bh1[512 + ecg + 1];
        bG0 = bi1[1024 + ecg]     + bh1[1024 + ecg];
        bG1 = bi1[1024 + ecg + 1] + bh1[1024 + ecg + 1];
        bO0 = bi1[1536 + ecg]     + bh1[1536 + ecg];
        bO1 = bi1[1536 + ecg + 1] + bh1[1536 + ecg + 1];
    }

    // staging coords
    const int sr = tid >> 4, ss = tid & 15;   // L0: 32 rows x 4 chunks
    const int r2 = tid >> 3, sb = tid & 7;    // L1: 64 rows x 8 chunks

    const short* i2hs = (const short*)i2h;
    uint pf0 = 0, pf1 = 0, pf2 = 0, pf3 = 0;  // L0 i2h prefetch
    if (!isL1) {
        const size_t tb = (size_t)bx * 1024 + eb * 32 + ecol;   // t = 0
        pf0 = *(const uint*)(i2hs + tb);
        pf1 = *(const uint*)(i2hs + tb + 16384);
        pf2 = *(const uint*)(i2hs + tb + 32768);
        pf3 = *(const uint*)(i2hs + tb + 49152);
    }
    float cr0 = 0.f, cr1 = 0.f;               // register-resident c state
    bool bail = false;

    for (int r = 0; r <= T; ++r) {
        const int t = isL1 ? (r - 1) : r;
        const bool act = isL1 ? (r >= 1) : (r < T);
        if (act) {
            // ---- stage operands -> LDS (bypass, fresh from LLC) ----
            if (!isL1) {
                const short* hp = (const short*)((t & 1) ? h0B : h0A);
                const short* p0 = hp + sr * 512 + (ss +  0) * 8;
                const short* p1 = hp + sr * 512 + (ss + 16) * 8;
                const short* p2 = hp + sr * 512 + (ss + 32) * 8;
                const short* p3 = hp + sr * 512 + (ss + 48) * 8;
                int4v v0, v1, v2, v3;
                asm volatile("global_load_dwordx4 %0, %1, off sc0 sc1" : "=v"(v0) : "v"(p0));
                asm volatile("global_load_dwordx4 %0, %1, off sc0 sc1" : "=v"(v1) : "v"(p1));
                asm volatile("global_load_dwordx4 %0, %1, off sc0 sc1" : "=v"(v2) : "v"(p2));
                asm volatile("global_load_dwordx4 %0, %1, off sc0 sc1" : "=v"(v3) : "v"(p3));
                asm volatile("s_waitcnt vmcnt(0)" ::: "memory");
                *(int4v*)&hs[((sr * 64 + ss +  0) ^ (sr & 7)) * 8] = v0;
                *(int4v*)&hs[((sr * 64 + ss + 16) ^ (sr & 7)) * 8] = v1;
                *(int4v*)&hs[((sr * 64 + ss + 32) ^ (sr & 7)) * 8] = v2;
                *(int4v*)&hs[((sr * 64 + ss + 48) ^ (sr & 7)) * 8] = v3;
            } else {
                const short* hp = (const short*)((t & 1) ? h1B : h1A);
                const short* s0 = (r2 < 32)
                    ? (const short*)y0 + ((size_t)r2 * T + t) * 512
                    : hp + (size_t)(r2 - 32) * 512;
                int4v v[8];
                #pragma unroll
                for (int i = 0; i < 8; ++i) {
                    const short* p = s0 + (sb + 8 * i) * 8;
                    asm volatile("global_load_dwordx4 %0, %1, off sc0 sc1" : "=v"(v[i]) : "v"(p));
                }
                asm volatile("s_waitcnt vmcnt(0)" ::: "memory");
                #pragma unroll
                for (int i = 0; i < 8; ++i)
                    *(int4v*)&hs[((r2 * 64 + sb + 8 * i) ^ (r2 & 7)) * 8] = v[i];
            }
            __syncthreads();

            // ---- GEMM: gates for this wave's 16 cols ----
            f32x4 acc0 = {}, acc1 = {};
            if (!isL1) {
                #pragma unroll
                for (int kk = 0; kk < 16; ++kk) {
                    const short8 a0 = *(const short8*)
                        &hs[((l15 * 64 + quad + kk * 4) ^ (l15 & 7)) * 8];
                    const short8 a1 = *(const short8*)
                        &hs[(((16 + l15) * 64 + quad + kk * 4) ^ (l15 & 7)) * 8];
                    acc0 = MFMA_BF16_16x16x32(a0, wf[kk], acc0);
                    acc1 = MFMA_BF16_16x16x32(a1, wf[kk], acc1);
                }
            } else {
                #pragma unroll
                for (int kk = 0; kk < 16; ++kk) {   // K 0..511: y0 @ Wi1
                    const short8 a0 = *(const short8*)
                        &hs[((l15 * 64 + quad + kk * 4) ^ (l15 & 7)) * 8];
                    const short8 a1 = *(const short8*)
                        &hs[(((16 + l15) * 64 + quad + kk * 4) ^ (l15 & 7)) * 8];
                    acc0 = MFMA_BF16_16x16x32(a0, wf[kk], acc0);
                    acc1 = MFMA_BF16_16x16x32(a1, wf[kk], acc1);
                }
                #pragma unroll
                for (int kk = 0; kk < 16; ++kk) {   // K 512..1023: h1 @ Wh1
                    const short8 a0 = *(const short8*)
                        &hs[(((32 + l15) * 64 + quad + kk * 4) ^ (l15 & 7)) * 8];
                    const short8 a1 = *(const short8*)
                        &hs[(((48 + l15) * 64 + quad + kk * 4) ^ (l15 & 7)) * 8];
                    acc0 = MFMA_BF16_16x16x32(a0, wf[16 + kk], acc0);
                    acc1 = MFMA_BF16_16x16x32(a1, wf[16 + kk], acc1);
                }
            }
            #pragma unroll
            for (int q = 0; q < 4; ++q) {
                gl[gate][quad * 4 + q][ch * 16 + l15]      = acc0[q];
                gl[gate][16 + quad * 4 + q][ch * 16 + l15] = acc1[q];
            }
            __syncthreads();

            // ---- elementwise ----
            const float2 gi = *(const float2*)&gl[0][eb][ecol];
            const float2 gf = *(const float2*)&gl[1][eb][ecol];
            const float2 gg = *(const float2*)&gl[2][eb][ecol];
            const float2 go = *(const float2*)&gl[3][eb][ecol];
            float iv0, iv1, fv0, fv1, gv0, gv1, ov0, ov1;
            if (!isL1) {
                iv0 = gi.x + bflo(pf0); iv1 = gi.y + bfhi(pf0);
                fv0 = gf.x + bflo(pf1); fv1 = gf.y + bfhi(pf1);
                gv0 = gg.x + bflo(pf2); gv1 = gg.y + bfhi(pf2);
                ov0 = go.x + bflo(pf3); ov1 = go.y + bfhi(pf3);
                // prefetch i2h for t+1
                const int tn = (t + 1 < T) ? (t + 1) : t;
                const size_t nb = (size_t)tn * 65536 + (size_t)bx * 1024 + eb * 32 + ecol;
                pf0 = *(const uint*)(i2hs + nb);
                pf1 = *(const uint*)(i2hs + nb + 16384);
                pf2 = *(const uint*)(i2hs + nb + 32768);
                pf3 = *(const uint*)(i2hs + nb + 49152);
            } else {
                iv0 = gi.x + bI0; iv1 = gi.y + bI1;
                fv0 = gf.x + bF0; fv1 = gf.y + bF1;
                gv0 = gg.x + bG0; gv1 = gg.y + bG1;
                ov0 = go.x + bO0; ov1 = go.y + bO1;
            }

            const float ig0 = 1.f / (1.f + __expf(-iv0));
            const float ig1 = 1.f / (1.f + __expf(-iv1));
            const float fg0 = 1.f / (1.f + __expf(-fv0));
            const float fg1 = 1.f / (1.f + __expf(-fv1));
            const float cg0 = 1.f - 2.f / (__expf(2.f * gv0) + 1.f);
            const float cg1 = 1.f - 2.f / (__expf(2.f * gv1) + 1.f);
            const float og0 = 1.f / (1.f + __expf(-ov0));
            const float og1 = 1.f / (1.f + __expf(-ov1));
            cr0 = fg0 * cr0 + ig0 * cg0;
            cr1 = fg1 * cr1 + ig1 * cg1;
            const float hn0 = og0 * (1.f - 2.f / (__expf(2.f * cr0) + 1.f));
            const float hn1 = og1 * (1.f - 2.f / (__expf(2.f * cr1) + 1.f));

            const uint hpk = (uint)(ushort)f2bf(hn0) | ((uint)(ushort)f2bf(hn1) << 16);
            if (!isL1) {
                short* hw = (short*)((t & 1) ? h0A : h0B);
                uint o1 = __hip_atomic_exchange((uint*)(hw + eb * 512 + ecg), hpk,
                                                __ATOMIC_RELAXED, __HIP_MEMORY_SCOPE_AGENT);
                uint o2 = __hip_atomic_exchange(
                    (uint*)((short*)y0 + ((size_t)eb * T + t) * 512 + ecg), hpk,
                    __ATOMIC_RELAXED, __HIP_MEMORY_SCOPE_AGENT);
                asm volatile("" : : "v"(o1), "v"(o2));  // keep returning forms
            } else {
                short* hw = (short*)((t & 1) ? h1A : h1B);
                uint o1 = __hip_atomic_exchange((uint*)(hw + eb * 512 + ecg), hpk,
                                                __ATOMIC_RELAXED, __HIP_MEMORY_SCOPE_AGENT);
                asm volatile("" : : "v"(o1));
                float2 yv; yv.x = hn0; yv.y = hn1;
                *(float2*)(y1 + ((size_t)eb * T + t) * 512 + ecg) = yv;
            }
        }

        if (r == T) break;                    // last round: no barrier

        // ---- fence-free device barrier (single spinner, hang-proof) ----
        __syncthreads();                       // drains exchanges (vmcnt 0)
        if (!bail) {
            if (tid == 0) {
                __hip_atomic_fetch_add(cnt, 1, __ATOMIC_RELAXED,
                                       __HIP_MEMORY_SCOPE_AGENT);
                const int target = NB * (r + 1);
                int iters = 0;
                while (__hip_atomic_load(cnt, __ATOMIC_RELAXED,
                                         __HIP_MEMORY_SCOPE_AGENT) < target) {
                    if (++iters > 1000000) { sBail = 1; break; }
                }
            }
            __syncthreads();
            if (sBail) bail = true;
        }
    }

    // final c
    if (!isL1) {
        c0o[eb * 512 + ecg]     = cr0;
        c0o[eb * 512 + ecg + 1] = cr1;
    } else {
        c1o[eb * 512 + ecg]     = cr0;
        c1o[eb * 512 + ecg + 1] = cr1;
    }
}

// ---------------------------------------------------------------------------
// Copy final h/c of both layers into d_out tail (fp32).
// ---------------------------------------------------------------------------
__global__ __launch_bounds__(256) void lstm_copy_finals(
    const __hip_bfloat16* __restrict__ h0, const __hip_bfloat16* __restrict__ h1,
    const float* __restrict__ c0, const float* __restrict__ c1,
    float* __restrict__ out)
{
    const int i = blockIdx.x * 256 + threadIdx.x;  // 0..16383
    out[i]         = __bfloat162float(h0[i]);
    out[16384 + i] = __bfloat162float(h1[i]);
    out[32768 + i] = c0[i];
    out[49152 + i] = c1[i];
}

extern "C" void kernel_launch(void* const* d_in, const int* in_sizes, int n_in,
                              void* d_out, int out_size, void* d_ws, size_t ws_size,
                              hipStream_t stream)
{
    const float* x   = (const float*)d_in[0];
    const float* Wi0 = (const float*)d_in[1];
    const float* bi0 = (const float*)d_in[2];
    const float* Wh0 = (const float*)d_in[3];
    const float* bh0 = (const float*)d_in[4];
    const float* Wi1 = (const float*)d_in[5];
    const float* bi1 = (const float*)d_in[6];
    const float* Wh1 = (const float*)d_in[7];
    const float* bh1 = (const float*)d_in[8];
    float* out = (float*)d_out;

    char* ws = (char*)d_ws;
    __hip_bfloat16* i2h  = (__hip_bfloat16*)(ws);
    __hip_bfloat16* y0   = (__hip_bfloat16*)(ws + 268435456ULL);
    __hip_bfloat16* h0a  = (__hip_bfloat16*)(ws + 335544320ULL);
    __hip_bfloat16* h0b  = (__hip_bfloat16*)(ws + 335577088ULL);
    __hip_bfloat16* h1a  = (__hip_bfloat16*)(ws + 335609856ULL);
    __hip_bfloat16* h1b  = (__hip_bfloat16*)(ws + 335642624ULL);
    float*          c0   = (float*)(ws + 335675392ULL);
    float*          c1   = (float*)(ws + 335740928ULL);

    // barrier counter at head of d_out's finals region (overwritten by
    // copy_finals at the end of the launch sequence).
    int* cnts = (int*)((char*)d_out + 134217728ULL);

    // zero initial h state (ws is poisoned before every call) + counter
    hipMemsetAsync(h0a, 0, 32768, stream);
    hipMemsetAsync(h1a, 0, 32768, stream);
    hipMemsetAsync(cnts, 0, 8, stream);

    // layer-0 i2h (big GEMM over all T)
    const dim3 ggrid(16, 512);  // N/128, M/128
    lstm_gemm_i2h<<<ggrid, 256, 0, stream>>>(x, Wi0, bi0, bh0, i2h);

    // fused 2-layer pipelined recurrence
    lstm_fused<<<32, 512, 0, stream>>>(
        i2h, Wh0, Wi1, Wh1, bi1, bh1,
        h0a, h0b, h1a, h1b, y0, out, c0, c1, cnts);

    // final (h, c): t=2047 (odd) wrote the 'a' buffers
    lstm_copy_finals<<<64, 256, 0, stream>>>(h0a, h1a, c0, c1, out + 33554432ULL);
}

// Round 7
// 12541.064 us; speedup vs baseline: 3.1989x; 1.1078x over previous
//
#include <hip/hip_runtime.h>
#include <hip/hip_bf16.h>
#include <cstdint>
#include <cstddef>

// Problem: 2-layer LSTM, B=32, T=2048, D=H=512, 4H=2048.
//
// Structure: layer-0 i2h precomputed by one big GEMM; BOTH LSTM recurrences
// run in ONE persistent kernel as a 1-step-lag software pipeline:
//   blocks  0..15 : layer 0, step t = r      (reads i2h0[t], h0; writes y0[t], h0')
//   blocks 16..31 : layer 1, step t = r - 1  (reads y0[t], h1; K=1024 GEMM
//                                             [y0;h1]@[Wi1;Wh1]^T; writes y1, h1')
// One device barrier per round: master+flag broadcast (round 5's 32 RMWs +
// 32 pollers on ONE line was ~4.5 us/round contention).
// Round-7 hardening: ABORT broadcast line — a timed-out spinner sets abort,
// all spinners check it every 1024 polls and bail immediately. Prevents the
// cascading-timeout mode (2048 x 500k-iter stalls -> container kill) that
// could explain round 6's infra-level failure.
//
// ws layout (bytes):
//   i2h  [T][4][16][32][32] bf16 : off 0,          size 268435456
//   y0   [B][T][H]  bf16        : off 268435456,   size 67108864
//   h0a  [32][512] bf16         : off 335544320,   size 32768
//   h0b                         : off 335577088
//   h1a                         : off 335609856
//   h1b                         : off 335642624
//   c0   [32][512] f32          : off 335675392,   size 65536
//   c1                          : off 335740928
// Barrier counter/flag/abort live in d_out's finals region (overwritten by
// copy_finals at the end of the launch sequence).

typedef __attribute__((ext_vector_type(8))) short short8;   // 8 x bf16
typedef __attribute__((ext_vector_type(4))) short short4v;  // 4 x bf16
typedef __attribute__((ext_vector_type(4))) float f32x4;
typedef __attribute__((ext_vector_type(4))) int int4v;

#define MFMA_BF16_16x16x32(A_, B_, C_) \
    __builtin_amdgcn_mfma_f32_16x16x32_bf16(A_, B_, C_, 0, 0, 0)

__device__ __forceinline__ short f2bf(float f) {
    __hip_bfloat16 b = __float2bfloat16(f);
    return *reinterpret_cast<short*>(&b);
}
__device__ __forceinline__ float bflo(uint u) {
    union { uint i; float f; } x; x.i = u << 16; return x.f;
}
__device__ __forceinline__ float bfhi(uint u) {
    union { uint i; float f; } x; x.i = u & 0xffff0000u; return x.f;
}
__device__ __forceinline__ short8 cvt8(const float* __restrict__ p) {
    const float4 v0 = ((const float4*)p)[0];
    const float4 v1 = ((const float4*)p)[1];
    short8 r;
    r[0]=f2bf(v0.x); r[1]=f2bf(v0.y); r[2]=f2bf(v0.z); r[3]=f2bf(v0.w);
    r[4]=f2bf(v1.x); r[5]=f2bf(v1.y); r[6]=f2bf(v1.z); r[7]=f2bf(v1.w);
    return r;
}

// ---------------------------------------------------------------------------
// i2h GEMM (layer 0 only): C[m][n] = sum_k x[m][k] * Wi0[n][k] + bi0[n]+bh0[n]
// out: PERMUTED [T][gate][colblk j][b][32] bf16 so each persist block reads
// full 128-B lines.
// ---------------------------------------------------------------------------
__global__ __launch_bounds__(256) void lstm_gemm_i2h(
    const float* __restrict__ A,
    const float* __restrict__ W,
    const float* __restrict__ bi,
    const float* __restrict__ bh,
    __hip_bfloat16* __restrict__ out)
{
    constexpr int K = 512;
    const int tid  = threadIdx.x;
    const int lane = tid & 63;
    const int w    = tid >> 6;
    const int wm   = w >> 1, wn = w & 1;
    const int quad = lane >> 4, l15 = lane & 15;
    const int m0 = blockIdx.y * 128;
    const int n0 = blockIdx.x * 128;

    __shared__ __align__(16) short sA[128 * 32];
    __shared__ __align__(16) short sB[128 * 32];

    f32x4 acc[4][4] = {};

    const int frow = tid >> 1;         // 0..127
    const int fcol = (tid & 1) * 16;   // 0 or 16

    for (int k0 = 0; k0 < K; k0 += 32) {
        __syncthreads();
        {
            const float* ap = A + (size_t)(m0 + frow) * K + k0 + fcol;
            float4 v0 = ((const float4*)ap)[0];
            float4 v1 = ((const float4*)ap)[1];
            float4 v2 = ((const float4*)ap)[2];
            float4 v3 = ((const float4*)ap)[3];
            short8 lo, hi;
            lo[0]=f2bf(v0.x); lo[1]=f2bf(v0.y); lo[2]=f2bf(v0.z); lo[3]=f2bf(v0.w);
            lo[4]=f2bf(v1.x); lo[5]=f2bf(v1.y); lo[6]=f2bf(v1.z); lo[7]=f2bf(v1.w);
            hi[0]=f2bf(v2.x); hi[1]=f2bf(v2.y); hi[2]=f2bf(v2.z); hi[3]=f2bf(v2.w);
            hi[4]=f2bf(v3.x); hi[5]=f2bf(v3.y); hi[6]=f2bf(v3.z); hi[7]=f2bf(v3.w);
            *(short8*)&sA[frow * 32 + fcol]     = lo;
            *(short8*)&sA[frow * 32 + fcol + 8] = hi;
        }
        {
            const float* wp = W + (size_t)(n0 + frow) * K + k0 + fcol;
            float4 v0 = ((const float4*)wp)[0];
            float4 v1 = ((const float4*)wp)[1];
            float4 v2 = ((const float4*)wp)[2];
            float4 v3 = ((const float4*)wp)[3];
            short8 lo, hi;
            lo[0]=f2bf(v0.x); lo[1]=f2bf(v0.y); lo[2]=f2bf(v0.z); lo[3]=f2bf(v0.w);
            lo[4]=f2bf(v1.x); lo[5]=f2bf(v1.y); lo[6]=f2bf(v1.z); lo[7]=f2bf(v1.w);
            hi[0]=f2bf(v2.x); hi[1]=f2bf(v2.y); hi[2]=f2bf(v2.z); hi[3]=f2bf(v2.w);
            hi[4]=f2bf(v3.x); hi[5]=f2bf(v3.y); hi[6]=f2bf(v3.z); hi[7]=f2bf(v3.w);
            *(short8*)&sB[frow * 32 + fcol]     = lo;
            *(short8*)&sB[frow * 32 + fcol + 8] = hi;
        }
        __syncthreads();

        short8 aF[4], bF[4];
        #pragma unroll
        for (int i = 0; i < 4; ++i) {
            aF[i] = *(const short8*)&sA[(wm * 64 + i * 16 + l15) * 32 + quad * 8];
            bF[i] = *(const short8*)&sB[(wn * 64 + i * 16 + l15) * 32 + quad * 8];
        }
        #pragma unroll
        for (int mi = 0; mi < 4; ++mi)
            #pragma unroll
            for (int ni = 0; ni < 4; ++ni)
                acc[mi][ni] = MFMA_BF16_16x16x32(aF[mi], bF[ni], acc[mi][ni]);
    }

    // epilogue: scatter into permuted i2h layout [t][g][j][b][c2]
    #pragma unroll
    for (int ni = 0; ni < 4; ++ni) {
        const int n = n0 + wn * 64 + ni * 16 + l15;
        const float bias = bi[n] + bh[n];
        const int g  = n >> 9;
        const int j  = (n >> 5) & 15;
        const int c2 = n & 31;
        #pragma unroll
        for (int mi = 0; mi < 4; ++mi) {
            #pragma unroll
            for (int r = 0; r < 4; ++r) {
                const int m = m0 + wm * 64 + mi * 16 + quad * 4 + r;
                const int b = m >> 11;      // m / 2048
                const int t = m & 2047;     // m % 2048
                out[((((size_t)t * 4 + g) * 16 + j) * 32 + b) * 32 + c2] =
                    __float2bfloat16(acc[mi][ni][r] + bias);
            }
        }
    }
}

// ---------------------------------------------------------------------------
// Fused 2-layer persistent recurrence (1-step-lag pipeline).
// 32 blocks x 512 threads. Block j (of its layer) owns h-cols [j*32, j*32+32)
// for all 4 gates. Weights register-resident.
//
// Cross-block data protocol (verified rounds 4-5):
//   writes: WITH-RETURN atomic exchange, agent scope (executed at LLC; vmcnt
//           ack = LLC response -> pre-barrier vmcnt(0) drain proves LLC
//           visibility). Applied to h0, h1, y0.
//   reads : cache-bypass global_load_dwordx4 sc0 sc1, staged into swizzled LDS.
//   barrier: __syncthreads -> tid0 fetch_add(cnt) -> block0 tid0 alone polls
//           cnt, publishes flag=r+1 (separate line) -> others read-poll flag
//           -> __syncthreads. Timeout => set ABORT (third line) => everyone
//           bails within 1024 polls. Hang-proof AND cascade-proof.
// ---------------------------------------------------------------------------
__global__ __launch_bounds__(512, 1) void lstm_fused(
    const __hip_bfloat16* __restrict__ i2h,   // [T][4][16][32][32] permuted
    const float* __restrict__ Wh0,            // [2048][512] f32
    const float* __restrict__ Wi1,            // [2048][512] f32
    const float* __restrict__ Wh1,            // [2048][512] f32
    const float* __restrict__ bi1,
    const float* __restrict__ bh1,
    __hip_bfloat16* __restrict__ h0A, __hip_bfloat16* __restrict__ h0B,
    __hip_bfloat16* __restrict__ h1A, __hip_bfloat16* __restrict__ h1B,
    __hip_bfloat16* __restrict__ y0,          // [B][T][H] bf16 (L0 out, L1 in)
    float* __restrict__ y1,                   // [B][T][H] f32 (d_out)
    float* __restrict__ c0o, float* __restrict__ c1o,
    int* __restrict__ cnt)   // cnt[0]=arrivals, cnt[64]=flag, cnt[96]=abort
{
    constexpr int T  = 2048;
    constexpr int NB = 32;
    const int tid  = threadIdx.x;
    const int lane = tid & 63;
    const int w    = tid >> 6;
    const int gate = w & 3;
    const int ch   = w >> 2;
    const int quad = lane >> 4, l15 = lane & 15;
    const bool isL1 = blockIdx.x >= 16;
    const bool isMaster = (blockIdx.x == 0);
    const int bx   = blockIdx.x & 15;
    const int col0 = bx * 32;
    int* const flag  = cnt + 64;              // separate line (256 B away)
    int* const abrt  = cnt + 96;              // separate line (384 B away)

    // staged operand rows: [64 rows][64 slots of 16B], slot ^= (row&7).
    // L0 uses rows 0..31 (h0). L1: rows 0..31 = y0[t], rows 32..63 = h1.
    __shared__ __align__(16) short hs[64 * 512];
    __shared__ __align__(16) float gl[4][32][34];
    __shared__ int sBail;
    if (tid == 0) sBail = 0;

    // ---- weights -> registers (fp32 -> bf16 inline, once) ----
    short8 wf[32];
    {
        const int wrow = gate * 512 + col0 + ch * 16 + l15;
        if (!isL1) {
            const float* p = Wh0 + (size_t)wrow * 512 + quad * 8;
            #pragma unroll
            for (int kk = 0; kk < 16; ++kk) wf[kk] = cvt8(p + kk * 32);
            #pragma unroll
            for (int kk = 16; kk < 32; ++kk) wf[kk] = wf[0]; // unused, keep defined
        } else {
            const float* pi = Wi1 + (size_t)wrow * 512 + quad * 8;
            const float* ph = Wh1 + (size_t)wrow * 512 + quad * 8;
            #pragma unroll
            for (int kk = 0; kk < 16; ++kk) wf[kk] = cvt8(pi + kk * 32);
            #pragma unroll
            for (int kk = 0; kk < 16; ++kk) wf[16 + kk] = cvt8(ph + kk * 32);
        }
    }

    // ---- elementwise ownership: thread -> (b, col, col+1) ----
    const int eb   = tid >> 4;
    const int ecol = (tid & 15) * 2;
    const int ecg  = col0 + ecol;

    // L1 bias (folded at elementwise time; L0 has bias in i2h)
    float bI0=0,bI1=0,bF0=0,bF1=0,bG0=0,bG1=0,bO0=0,bO1=0;
    if (isL1) {
        bI0 = bi1[ecg]            + bh1[ecg];
        bI1 = bi1[ecg + 1]        + bh1[ecg + 1];
        bF0 = bi1[512 + ecg]      + bh1[512 + ecg];
        bF1 = bi1[512 + ecg + 1]  + bh1[512 + ecg + 1];
        bG0 = bi1[1024 + ecg]     + bh1[1024 + ecg];
        bG1 = bi1[1024 + ecg + 1] + bh1[1024 + ecg + 1];
        bO0 = bi1[1536 + ecg]     + bh1[1536 + ecg];
        bO1 = bi1[1536 + ecg + 1] + bh1[1536 + ecg + 1];
    }

    // staging coords
    const int sr = tid >> 4, ss = tid & 15;   // L0: 32 rows x 4 chunks
    const int r2 = tid >> 3, sb = tid & 7;    // L1: 64 rows x 8 chunks

    const short* i2hs = (const short*)i2h;
    uint pf0 = 0, pf1 = 0, pf2 = 0, pf3 = 0;  // L0 i2h prefetch
    if (!isL1) {
        const size_t tb = (size_t)bx * 1024 + eb * 32 + ecol;   // t = 0
        pf0 = *(const uint*)(i2hs + tb);
        pf1 = *(const uint*)(i2hs + tb + 16384);
        pf2 = *(const uint*)(i2hs + tb + 32768);
        pf3 = *(const uint*)(i2hs + tb + 49152);
    }
    float cr0 = 0.f, cr1 = 0.f;               // register-resident c state
    bool bail = false;

    for (int r = 0; r <= T; ++r) {
        const int t = isL1 ? (r - 1) : r;
        const bool act = isL1 ? (r >= 1) : (r < T);
        if (act) {
            // ---- stage operands -> LDS (bypass, fresh from LLC) ----
            if (!isL1) {
                const short* hp = (const short*)((t & 1) ? h0B : h0A);
                const short* p0 = hp + sr * 512 + (ss +  0) * 8;
                const short* p1 = hp + sr * 512 + (ss + 16) * 8;
                const short* p2 = hp + sr * 512 + (ss + 32) * 8;
                const short* p3 = hp + sr * 512 + (ss + 48) * 8;
                int4v v0, v1, v2, v3;
                asm volatile("global_load_dwordx4 %0, %1, off sc0 sc1" : "=v"(v0) : "v"(p0));
                asm volatile("global_load_dwordx4 %0, %1, off sc0 sc1" : "=v"(v1) : "v"(p1));
                asm volatile("global_load_dwordx4 %0, %1, off sc0 sc1" : "=v"(v2) : "v"(p2));
                asm volatile("global_load_dwordx4 %0, %1, off sc0 sc1" : "=v"(v3) : "v"(p3));
                asm volatile("s_waitcnt vmcnt(0)" ::: "memory");
                *(int4v*)&hs[((sr * 64 + ss +  0) ^ (sr & 7)) * 8] = v0;
                *(int4v*)&hs[((sr * 64 + ss + 16) ^ (sr & 7)) * 8] = v1;
                *(int4v*)&hs[((sr * 64 + ss + 32) ^ (sr & 7)) * 8] = v2;
                *(int4v*)&hs[((sr * 64 + ss + 48) ^ (sr & 7)) * 8] = v3;
            } else {
                const short* hp = (const short*)((t & 1) ? h1B : h1A);
                const short* s0 = (r2 < 32)
                    ? (const short*)y0 + ((size_t)r2 * T + t) * 512
                    : hp + (size_t)(r2 - 32) * 512;
                int4v v[8];
                #pragma unroll
                for (int i = 0; i < 8; ++i) {
                    const short* p = s0 + (sb + 8 * i) * 8;
                    asm volatile("global_load_dwordx4 %0, %1, off sc0 sc1" : "=v"(v[i]) : "v"(p));
                }
                asm volatile("s_waitcnt vmcnt(0)" ::: "memory");
                #pragma unroll
                for (int i = 0; i < 8; ++i)
                    *(int4v*)&hs[((r2 * 64 + sb + 8 * i) ^ (r2 & 7)) * 8] = v[i];
            }
            __syncthreads();

            // ---- GEMM: gates for this wave's 16 cols ----
            f32x4 acc0 = {}, acc1 = {};
            if (!isL1) {
                #pragma unroll
                for (int kk = 0; kk < 16; ++kk) {
                    const short8 a0 = *(const short8*)
                        &hs[((l15 * 64 + quad + kk * 4) ^ (l15 & 7)) * 8];
                    const short8 a1 = *(const short8*)
                        &hs[(((16 + l15) * 64 + quad + kk * 4) ^ (l15 & 7)) * 8];
                    acc0 = MFMA_BF16_16x16x32(a0, wf[kk], acc0);
                    acc1 = MFMA_BF16_16x16x32(a1, wf[kk], acc1);
                }
            } else {
                #pragma unroll
                for (int kk = 0; kk < 16; ++kk) {   // K 0..511: y0 @ Wi1
                    const short8 a0 = *(const short8*)
                        &hs[((l15 * 64 + quad + kk * 4) ^ (l15 & 7)) * 8];
                    const short8 a1 = *(const short8*)
                        &hs[(((16 + l15) * 64 + quad + kk * 4) ^ (l15 & 7)) * 8];
                    acc0 = MFMA_BF16_16x16x32(a0, wf[kk], acc0);
                    acc1 = MFMA_BF16_16x16x32(a1, wf[kk], acc1);
                }
                #pragma unroll
                for (int kk = 0; kk < 16; ++kk) {   // K 512..1023: h1 @ Wh1
                    const short8 a0 = *(const short8*)
                        &hs[(((32 + l15) * 64 + quad + kk * 4) ^ (l15 & 7)) * 8];
                    const short8 a1 = *(const short8*)
                        &hs[(((48 + l15) * 64 + quad + kk * 4) ^ (l15 & 7)) * 8];
                    acc0 = MFMA_BF16_16x16x32(a0, wf[16 + kk], acc0);
                    acc1 = MFMA_BF16_16x16x32(a1, wf[16 + kk], acc1);
                }
            }
            #pragma unroll
            for (int q = 0; q < 4; ++q) {
                gl[gate][quad * 4 + q][ch * 16 + l15]      = acc0[q];
                gl[gate][16 + quad * 4 + q][ch * 16 + l15] = acc1[q];
            }
            __syncthreads();

            // ---- elementwise ----
            const float2 gi = *(const float2*)&gl[0][eb][ecol];
            const float2 gf = *(const float2*)&gl[1][eb][ecol];
            const float2 gg = *(const float2*)&gl[2][eb][ecol];
            const float2 go = *(const float2*)&gl[3][eb][ecol];
            float iv0, iv1, fv0, fv1, gv0, gv1, ov0, ov1;
            if (!isL1) {
                iv0 = gi.x + bflo(pf0); iv1 = gi.y + bfhi(pf0);
                fv0 = gf.x + bflo(pf1); fv1 = gf.y + bfhi(pf1);
                gv0 = gg.x + bflo(pf2); gv1 = gg.y + bfhi(pf2);
                ov0 = go.x + bflo(pf3); ov1 = go.y + bfhi(pf3);
                // prefetch i2h for t+1
                const int tn = (t + 1 < T) ? (t + 1) : t;
                const size_t nb = (size_t)tn * 65536 + (size_t)bx * 1024 + eb * 32 + ecol;
                pf0 = *(const uint*)(i2hs + nb);
                pf1 = *(const uint*)(i2hs + nb + 16384);
                pf2 = *(const uint*)(i2hs + nb + 32768);
                pf3 = *(const uint*)(i2hs + nb + 49152);
            } else {
                iv0 = gi.x + bI0; iv1 = gi.y + bI1;
                fv0 = gf.x + bF0; fv1 = gf.y + bF1;
                gv0 = gg.x + bG0; gv1 = gg.y + bG1;
                ov0 = go.x + bO0; ov1 = go.y + bO1;
            }

            const float ig0 = 1.f / (1.f + __expf(-iv0));
            const float ig1 = 1.f / (1.f + __expf(-iv1));
            const float fg0 = 1.f / (1.f + __expf(-fv0));
            const float fg1 = 1.f / (1.f + __expf(-fv1));
            const float cg0 = 1.f - 2.f / (__expf(2.f * gv0) + 1.f);
            const float cg1 = 1.f - 2.f / (__expf(2.f * gv1) + 1.f);
            const float og0 = 1.f / (1.f + __expf(-ov0));
            const float og1 = 1.f / (1.f + __expf(-ov1));
            cr0 = fg0 * cr0 + ig0 * cg0;
            cr1 = fg1 * cr1 + ig1 * cg1;
            const float hn0 = og0 * (1.f - 2.f / (__expf(2.f * cr0) + 1.f));
            const float hn1 = og1 * (1.f - 2.f / (__expf(2.f * cr1) + 1.f));

            const uint hpk = (uint)(ushort)f2bf(hn0) | ((uint)(ushort)f2bf(hn1) << 16);
            if (!isL1) {
                short* hw = (short*)((t & 1) ? h0A : h0B);
                uint o1 = __hip_atomic_exchange((uint*)(hw + eb * 512 + ecg), hpk,
                                                __ATOMIC_RELAXED, __HIP_MEMORY_SCOPE_AGENT);
                uint o2 = __hip_atomic_exchange(
                    (uint*)((short*)y0 + ((size_t)eb * T + t) * 512 + ecg), hpk,
                    __ATOMIC_RELAXED, __HIP_MEMORY_SCOPE_AGENT);
                asm volatile("" : : "v"(o1), "v"(o2));  // keep returning forms
            } else {
                short* hw = (short*)((t & 1) ? h1A : h1B);
                uint o1 = __hip_atomic_exchange((uint*)(hw + eb * 512 + ecg), hpk,
                                                __ATOMIC_RELAXED, __HIP_MEMORY_SCOPE_AGENT);
                asm volatile("" : : "v"(o1));
                float2 yv; yv.x = hn0; yv.y = hn1;
                *(float2*)(y1 + ((size_t)eb * T + t) * 512 + ecg) = yv;
            }
        }

        if (r == T) break;                    // last round: no barrier

        // ---- master+flag device barrier (hang- and cascade-proof) ----
        __syncthreads();                       // drains exchanges (vmcnt 0)
        if (!bail) {
            if (tid == 0) {
                __hip_atomic_fetch_add(cnt, 1, __ATOMIC_RELAXED,
                                       __HIP_MEMORY_SCOPE_AGENT);
                if (isMaster) {
                    // only the master polls the arrival line
                    const int target = NB * (r + 1);
                    int iters = 0;
                    while (__hip_atomic_load(cnt, __ATOMIC_RELAXED,
                                             __HIP_MEMORY_SCOPE_AGENT) < target) {
                        __builtin_amdgcn_s_sleep(1);
                        ++iters;
                        if ((iters & 1023) == 0 &&
                            __hip_atomic_load(abrt, __ATOMIC_RELAXED,
                                              __HIP_MEMORY_SCOPE_AGENT)) {
                            sBail = 1; break;
                        }
                        if (iters > 500000) {
                            uint oa = __hip_atomic_exchange((uint*)abrt, 1u,
                                         __ATOMIC_RELAXED, __HIP_MEMORY_SCOPE_AGENT);
                            asm volatile("" : : "v"(oa));
                            sBail = 1; break;
                        }
                    }
                    if (!sBail) {
                        // broadcast release on a separate line (with-return =>
                        // LLC-committed before master proceeds)
                        uint of = __hip_atomic_exchange((uint*)flag, (uint)(r + 1),
                                                        __ATOMIC_RELAXED,
                                                        __HIP_MEMORY_SCOPE_AGENT);
                        asm volatile("" : : "v"(of));
                    }
                } else {
                    // everyone else read-polls the flag line only
                    int iters = 0;
                    while ((int)__hip_atomic_load((uint*)flag, __ATOMIC_RELAXED,
                                                  __HIP_MEMORY_SCOPE_AGENT) < r + 1) {
                        __builtin_amdgcn_s_sleep(1);
                        ++iters;
                        if ((iters & 1023) == 0 &&
                            __hip_atomic_load(abrt, __ATOMIC_RELAXED,
                                              __HIP_MEMORY_SCOPE_AGENT)) {
                            sBail = 1; break;
                        }
                        if (iters > 500000) {
                            uint oa = __hip_atomic_exchange((uint*)abrt, 1u,
                                         __ATOMIC_RELAXED, __HIP_MEMORY_SCOPE_AGENT);
                            asm volatile("" : : "v"(oa));
                            sBail = 1; break;
                        }
                    }
                }
            }
            __syncthreads();
            if (sBail) bail = true;
        }
    }

    // final c
    if (!isL1) {
        c0o[eb * 512 + ecg]     = cr0;
        c0o[eb * 512 + ecg + 1] = cr1;
    } else {
        c1o[eb * 512 + ecg]     = cr0;
        c1o[eb * 512 + ecg + 1] = cr1;
    }
}

// ---------------------------------------------------------------------------
// Copy final h/c of both layers into d_out tail (fp32).
// ---------------------------------------------------------------------------
__global__ __launch_bounds__(256) void lstm_copy_finals(
    const __hip_bfloat16* __restrict__ h0, const __hip_bfloat16* __restrict__ h1,
    const float* __restrict__ c0, const float* __restrict__ c1,
    float* __restrict__ out)
{
    const int i = blockIdx.x * 256 + threadIdx.x;  // 0..16383
    out[i]         = __bfloat162float(h0[i]);
    out[16384 + i] = __bfloat162float(h1[i]);
    out[32768 + i] = c0[i];
    out[49152 + i] = c1[i];
}

extern "C" void kernel_launch(void* const* d_in, const int* in_sizes, int n_in,
                              void* d_out, int out_size, void* d_ws, size_t ws_size,
                              hipStream_t stream)
{
    const float* x   = (const float*)d_in[0];
    const float* Wi0 = (const float*)d_in[1];
    const float* bi0 = (const float*)d_in[2];
    const float* Wh0 = (const float*)d_in[3];
    const float* bh0 = (const float*)d_in[4];
    const float* Wi1 = (const float*)d_in[5];
    const float* bi1 = (const float*)d_in[6];
    const float* Wh1 = (const float*)d_in[7];
    const float* bh1 = (const float*)d_in[8];
    float* out = (float*)d_out;

    char* ws = (char*)d_ws;
    __hip_bfloat16* i2h  = (__hip_bfloat16*)(ws);
    __hip_bfloat16* y0   = (__hip_bfloat16*)(ws + 268435456ULL);
    __hip_bfloat16* h0a  = (__hip_bfloat16*)(ws + 335544320ULL);
    __hip_bfloat16* h0b  = (__hip_bfloat16*)(ws + 335577088ULL);
    __hip_bfloat16* h1a  = (__hip_bfloat16*)(ws + 335609856ULL);
    __hip_bfloat16* h1b  = (__hip_bfloat16*)(ws + 335642624ULL);
    float*          c0   = (float*)(ws + 335675392ULL);
    float*          c1   = (float*)(ws + 335740928ULL);

    // barrier counter (cnt[0]) + flag (cnt[64]) + abort (cnt[96]) at head of
    // d_out's finals region (overwritten by copy_finals at sequence end).
    int* cnts = (int*)((char*)d_out + 134217728ULL);

    // zero initial h state (ws is poisoned before every call) + barrier words
    hipMemsetAsync(h0a, 0, 32768, stream);
    hipMemsetAsync(h1a, 0, 32768, stream);
    hipMemsetAsync(cnts, 0, 512, stream);

    // layer-0 i2h (big GEMM over all T)
    const dim3 ggrid(16, 512);  // N/128, M/128
    lstm_gemm_i2h<<<ggrid, 256, 0, stream>>>(x, Wi0, bi0, bh0, i2h);

    // fused 2-layer pipelined recurrence
    lstm_fused<<<32, 512, 0, stream>>>(
        i2h, Wh0, Wi1, Wh1, bi1, bh1,
        h0a, h0b, h1a, h1b, y0, out, c0, c1, cnts);

    // final (h, c): t=2047 (odd) wrote the 'a' buffers
    lstm_copy_finals<<<64, 256, 0, stream>>>(h0a, h1a, c0, c1, out + 33554432ULL);
}